// Round 1
// baseline (28989.920 us; speedup 1.0000x reference)
//
#include <hip/hip_runtime.h>
#include <math.h>

#define EOS_ID 2
#define START_ID 1
#define NEGV (-1e9f)

__device__ __forceinline__ float sigmoidf_(float x) { return 1.f / (1.f + expf(-x)); }

// ---------------------------------------------------------------------------
// Generic fp32 GEMM: C[M,N] = Aload[M,K] @ B[K,N] (+bias)
// AMODE 0: plain A row-major [M,K]
// AMODE 1: decoder concat row: k<512 -> dec_emb[tok[r]][k]; k<1024 -> attn[r][k-512];
//          else h[r][k-1024]   (A = dec_emb base)
// AMODE 2: encoder embedding gather: row r = s*32+b, token = tokp[b*128+s]
// B row split: row k taken from B1 if k<ksplit else B2[k-ksplit] (both ld = N)
// ---------------------------------------------------------------------------
template<int BM, int BN, int BK, int AMODE>
__global__ void __launch_bounds__(256) gemm_k(
    const float* __restrict__ A, const float* __restrict__ B1,
    const float* __restrict__ B2, int ksplit,
    const float* __restrict__ bias, float* __restrict__ C,
    int M, int N, int K,
    const int* __restrict__ tokp, const float* __restrict__ attnp,
    const float* __restrict__ hp)
{
    static_assert(BN == 64, "epilogue assumes TN==4");
    constexpr int TM = BM / 16, TN = BN / 16;
    __shared__ __align__(16) float As[BK][BM];
    __shared__ __align__(16) float Bs[BK][BN];
    const int tid = threadIdx.x;
    const int n0 = blockIdx.x * BN, m0 = blockIdx.y * BM;
    const int tx = tid & 15, ty = tid >> 4;
    (void)M;

    float acc[TM][TN];
    #pragma unroll
    for (int i = 0; i < TM; i++)
        #pragma unroll
        for (int j = 0; j < TN; j++) acc[i][j] = 0.f;

    constexpr int A4 = BM * BK / 4;  // float4 loads for A tile
    constexpr int B4 = BK * BN / 4;  // float4 loads for B tile

    for (int k0 = 0; k0 < K; k0 += BK) {
        if (A4 >= 256 || tid < A4) {
            const int am  = tid / (BK / 4);
            const int ak4 = tid % (BK / 4);
            const int kg  = k0 + ak4 * 4;
            float4 av;
            if (AMODE == 0) {
                av = *reinterpret_cast<const float4*>(A + (size_t)(m0 + am) * K + kg);
            } else if (AMODE == 1) {
                const int r = m0 + am;
                if (kg < 512)
                    av = *reinterpret_cast<const float4*>(A + (size_t)tokp[r] * 512 + kg);
                else if (kg < 1024)
                    av = *reinterpret_cast<const float4*>(attnp + (size_t)r * 512 + (kg - 512));
                else
                    av = *reinterpret_cast<const float4*>(hp + (size_t)r * 512 + (kg - 1024));
            } else {  // AMODE 2
                const int r = m0 + am;
                const int s = r >> 5, b = r & 31;
                const int tk = tokp[b * 128 + s];
                av = *reinterpret_cast<const float4*>(A + (size_t)tk * 512 + kg);
            }
            As[ak4 * 4 + 0][am] = av.x;
            As[ak4 * 4 + 1][am] = av.y;
            As[ak4 * 4 + 2][am] = av.z;
            As[ak4 * 4 + 3][am] = av.w;
        }
        if (B4 >= 256 || tid < B4) {
            const int bk  = tid / (BN / 4);
            const int bn4 = tid % (BN / 4);
            const int kg  = k0 + bk;
            const float* src = (kg < ksplit) ? (B1 + (size_t)kg * N)
                                             : (B2 + (size_t)(kg - ksplit) * N);
            *reinterpret_cast<float4*>(&Bs[bk][bn4 * 4]) =
                *reinterpret_cast<const float4*>(src + n0 + bn4 * 4);
        }
        __syncthreads();
        #pragma unroll
        for (int kk = 0; kk < BK; kk++) {
            float af[TM], bf[TN];
            if constexpr (TM == 4) {
                const float4 t4 = *reinterpret_cast<const float4*>(&As[kk][ty * TM]);
                af[0] = t4.x; af[1] = t4.y; af[2] = t4.z; af[3] = t4.w;
            } else {
                const float2 t2 = *reinterpret_cast<const float2*>(&As[kk][ty * TM]);
                af[0] = t2.x; af[1] = t2.y;
            }
            const float4 b4 = *reinterpret_cast<const float4*>(&Bs[kk][tx * TN]);
            bf[0] = b4.x; bf[1] = b4.y; bf[2] = b4.z; bf[3] = b4.w;
            #pragma unroll
            for (int i = 0; i < TM; i++)
                #pragma unroll
                for (int j = 0; j < TN; j++) acc[i][j] += af[i] * bf[j];
        }
        __syncthreads();
    }

    float bv[TN];
    #pragma unroll
    for (int j = 0; j < TN; j++) bv[j] = bias ? bias[n0 + tx * TN + j] : 0.f;
    #pragma unroll
    for (int i = 0; i < TM; i++) {
        float4 o;
        o.x = acc[i][0] + bv[0]; o.y = acc[i][1] + bv[1];
        o.z = acc[i][2] + bv[2]; o.w = acc[i][3] + bv[3];
        *reinterpret_cast<float4*>(C + (size_t)(m0 + ty * TM + i) * N + n0 + tx * TN) = o;
    }
}

// ---------------------------------------------------------------------------
// init: zero enc_c [32*512] and hzero [512]
// ---------------------------------------------------------------------------
__global__ void __launch_bounds__(256) init_misc_k(float* __restrict__ enc_c,
                                                   float* __restrict__ hzero)
{
    const int idx = blockIdx.x * 256 + threadIdx.x;
    if (idx < 32 * 512) enc_c[idx] = 0.f;
    if (idx < 512) hzero[idx] = 0.f;
}

// ---------------------------------------------------------------------------
// Encoder LSTM step. Grid (8 jtiles, 16 bgroups), block 256.
// wg covers 2 batch rows x 64 j-indices x 4 gates. h_prev staged in LDS.
// ---------------------------------------------------------------------------
__global__ void __launch_bounds__(256) enc_step_k(
    const float* __restrict__ Xz_t,    // [32][2048] precomputed x@W+b for this t
    const float* __restrict__ hprev,   // row b at hprev + b*hstride
    long hstride,
    const float* __restrict__ U,       // U_enc [512][2048]
    float* __restrict__ c,             // enc_c [32][512], in-place
    float* __restrict__ hout,          // enc_out + t*512; row b at b*128*512
    int tstep)
{
    __shared__ __align__(16) float hs[512][2];  // transposed: hs[k][bb]
    __shared__ float zst[2][4][64];
    const int tid = threadIdx.x;
    const int jt = blockIdx.x;   // 0..7
    const int b0 = blockIdx.y * 2;
    (void)tstep;

    {   // stage h_prev rows (2 x 512 floats)
        const int bb = tid >> 7, k4 = tid & 127;
        const float4 hv = *reinterpret_cast<const float4*>(
            hprev + (size_t)(b0 + bb) * hstride + k4 * 4);
        hs[k4 * 4 + 0][bb] = hv.x; hs[k4 * 4 + 1][bb] = hv.y;
        hs[k4 * 4 + 2][bb] = hv.z; hs[k4 * 4 + 3][bb] = hv.w;
    }
    __syncthreads();

    const int j = tid & 63, g = tid >> 6;
    const int col = g * 512 + jt * 64 + j;
    float a0 = Xz_t[(size_t)b0 * 2048 + col];
    float a1 = Xz_t[(size_t)(b0 + 1) * 2048 + col];
    #pragma unroll 8
    for (int k = 0; k < 512; k++) {
        const float u = U[(size_t)k * 2048 + col];
        const float2 h2 = *reinterpret_cast<const float2*>(&hs[k][0]);
        a0 += h2.x * u;
        a1 += h2.y * u;
    }
    zst[0][g][j] = a0;
    zst[1][g][j] = a1;
    __syncthreads();

    if (tid < 128) {
        const int bb = tid >> 6, jj = tid & 63;
        const int b = b0 + bb;
        const float iv = sigmoidf_(zst[bb][0][jj]);
        const float fv = sigmoidf_(zst[bb][1][jj]);
        const float gv = tanhf(zst[bb][2][jj]);
        const float ov = sigmoidf_(zst[bb][3][jj]);
        const int jglob = jt * 64 + jj;
        const size_t ci = (size_t)b * 512 + jglob;
        const float cv = fv * c[ci] + iv * gv;
        c[ci] = cv;
        hout[(size_t)b * 128 * 512 + jglob] = ov * tanhf(cv);
    }
}

// ---------------------------------------------------------------------------
// Decoder init: tile hN/cN over beams, zero attn, init cum/finished/tok
// ---------------------------------------------------------------------------
__global__ void __launch_bounds__(256) init_dec_k(
    const float* __restrict__ enc_out, const float* __restrict__ enc_c,
    float* __restrict__ h_buf, float* __restrict__ c_buf, float* __restrict__ attn_buf,
    float* __restrict__ cum, int* __restrict__ fin, int* __restrict__ tok)
{
    const int idx = blockIdx.x * 256 + threadIdx.x;  // < 128*512
    const int r = idx >> 9, jcol = idx & 511;
    const int b = r >> 2, kbeam = r & 3;
    h_buf[idx] = enc_out[((size_t)b * 128 + 127) * 512 + jcol];
    c_buf[idx] = enc_c[(size_t)b * 512 + jcol];
    attn_buf[idx] = 0.f;
    if (jcol == 0) {
        cum[r] = (kbeam == 0) ? 0.f : NEGV;
        fin[r] = 0;
        tok[r] = START_ID;
    }
}

// ---------------------------------------------------------------------------
// LSTM gate math for decoder: z[128][2048], c_in -> c_new + cell_out (Acat left)
// ---------------------------------------------------------------------------
__global__ void __launch_bounds__(256) gates_k(
    const float* __restrict__ z, const float* __restrict__ c_in,
    float* __restrict__ c_out, float* __restrict__ Acat)
{
    const int idx = blockIdx.x * 256 + threadIdx.x;  // < 65536
    const int r = idx >> 9, j = idx & 511;
    const size_t base = (size_t)r * 2048;
    const float iv = sigmoidf_(z[base + j]);
    const float fv = sigmoidf_(z[base + 512 + j]);
    const float gv = tanhf(z[base + 1024 + j]);
    const float ov = sigmoidf_(z[base + 1536 + j]);
    const float cv = fv * c_in[idx] + iv * gv;
    c_out[idx] = cv;
    Acat[(size_t)r * 1024 + j] = ov * tanhf(cv);
}

// ---------------------------------------------------------------------------
// Luong attention per (b,beam) row: scores -> softmax -> ctx (Acat right half)
// ---------------------------------------------------------------------------
__global__ void __launch_bounds__(256) attention_k(
    const float* __restrict__ Acat,     // [128][1024], left = cell_out
    const float* __restrict__ keys,     // [32][128][512]
    const float* __restrict__ enc_out,  // [32][128][512] (values)
    float* __restrict__ AcatW)
{
    __shared__ __align__(16) float q[512];
    __shared__ float sc[128];
    __shared__ float red[128];
    const int r = blockIdx.x;
    const int b = r >> 2;
    const int tid = threadIdx.x;

    for (int i = tid; i < 128; i += 256)
        reinterpret_cast<float4*>(q)[i] =
            reinterpret_cast<const float4*>(Acat + (size_t)r * 1024)[i];
    __syncthreads();

    if (tid < 128) {
        const float* kr = keys + ((size_t)b * 128 + tid) * 512;
        float acc = 0.f;
        for (int k4 = 0; k4 < 128; k4++) {
            const float4 qa = reinterpret_cast<const float4*>(q)[k4];
            const float4 kb = reinterpret_cast<const float4*>(kr)[k4];
            acc += qa.x * kb.x + qa.y * kb.y + qa.z * kb.z + qa.w * kb.w;
        }
        sc[tid] = acc;
    }
    __syncthreads();
    // max
    if (tid < 64) red[tid] = fmaxf(sc[tid], sc[tid + 64]);
    __syncthreads();
    for (int st = 32; st >= 1; st >>= 1) {
        if (tid < st) red[tid] = fmaxf(red[tid], red[tid + st]);
        __syncthreads();
    }
    const float m = red[0];
    __syncthreads();
    if (tid < 128) sc[tid] = expf(sc[tid] - m);
    __syncthreads();
    if (tid < 64) red[tid] = sc[tid] + sc[tid + 64];
    __syncthreads();
    for (int st = 32; st >= 1; st >>= 1) {
        if (tid < st) red[tid] += red[tid + st];
        __syncthreads();
    }
    const float S = red[0];
    __syncthreads();
    if (tid < 128) sc[tid] = sc[tid] / S;
    __syncthreads();

    float a0 = 0.f, a1 = 0.f;
    for (int s = 0; s < 128; s++) {
        const float w = sc[s];
        const float* vr = enc_out + ((size_t)b * 128 + s) * 512;
        a0 += w * vr[tid];
        a1 += w * vr[tid + 256];
    }
    AcatW[(size_t)r * 1024 + 512 + tid] = a0;
    AcatW[(size_t)r * 1024 + 512 + tid + 256] = a1;
}

// ---------------------------------------------------------------------------
// Fused logsumexp + masked beam top-4 + state gather. One wg per batch b.
// Tie-break matches jax.lax.top_k: value desc, then lower flat index.
// ---------------------------------------------------------------------------
__global__ void __launch_bounds__(256) topk_gather_k(
    const float* __restrict__ logits,  // [128][32000]
    float* __restrict__ cum, int* __restrict__ fin, int* __restrict__ tok,
    const float* __restrict__ Acat,    // cell_out in left half [128][1024]
    const float* __restrict__ c_new, const float* __restrict__ attn_new,
    float* __restrict__ h_buf, float* __restrict__ c_buf, float* __restrict__ attn_buf,
    int* __restrict__ parents_t, int* __restrict__ toks_t)
{
    const int b = blockIdx.x;
    const int tid = threadIdx.x;
    __shared__ float red[256];
    __shared__ float lZ[4], oldcum[4];
    __shared__ int oldfin[4];
    __shared__ float sv[1024];
    __shared__ int si[1024];
    __shared__ float rv[256];
    __shared__ int ri[256], rp[256];
    __shared__ float wv[4];
    __shared__ int wi[4], par[4];

    if (tid < 4) {
        oldcum[tid] = cum[b * 4 + tid];
        oldfin[tid] = fin[b * 4 + tid];
    }
    __syncthreads();

    // per-beam log_softmax normalizer: logZ = max + log(sum exp(x-max))
    for (int k = 0; k < 4; k++) {
        const float* row = logits + (size_t)(b * 4 + k) * 32000;
        float m = -INFINITY;
        for (int v = tid; v < 32000; v += 256) m = fmaxf(m, row[v]);
        red[tid] = m;
        __syncthreads();
        for (int st = 128; st >= 1; st >>= 1) {
            if (tid < st) red[tid] = fmaxf(red[tid], red[tid + st]);
            __syncthreads();
        }
        m = red[0];
        __syncthreads();
        float s = 0.f;
        for (int v = tid; v < 32000; v += 256) s += expf(row[v] - m);
        red[tid] = s;
        __syncthreads();
        for (int st = 128; st >= 1; st >>= 1) {
            if (tid < st) red[tid] += red[tid + st];
            __syncthreads();
        }
        if (tid == 0) lZ[k] = m + logf(red[0]);
        __syncthreads();
    }

    // thread-local top-4 over 128000 candidates (ix increasing per thread)
    float bvv[4] = {-INFINITY, -INFINITY, -INFINITY, -INFINITY};
    int bii[4] = {0x7FFFFFFF, 0x7FFFFFFF, 0x7FFFFFFF, 0x7FFFFFFF};
    for (int ix = tid; ix < 128000; ix += 256) {
        const int k = ix / 32000;
        const int v = ix - k * 32000;
        float val;
        if (oldfin[k])
            val = oldcum[k] + ((v == EOS_ID) ? 0.f : NEGV);
        else
            val = oldcum[k] + (logits[(size_t)(b * 4 + k) * 32000 + v] - lZ[k]);
        if (val > bvv[3]) {
            bvv[3] = val; bii[3] = ix;
            #pragma unroll
            for (int j = 3; j > 0; j--) {
                if (bvv[j] > bvv[j - 1]) {
                    const float tv = bvv[j]; bvv[j] = bvv[j - 1]; bvv[j - 1] = tv;
                    const int ti = bii[j]; bii[j] = bii[j - 1]; bii[j - 1] = ti;
                }
            }
        }
    }
    #pragma unroll
    for (int j = 0; j < 4; j++) { sv[tid * 4 + j] = bvv[j]; si[tid * 4 + j] = bii[j]; }
    __syncthreads();

    // 4 extraction rounds of global argmax (value desc, index asc)
    for (int rr = 0; rr < 4; rr++) {
        float lv = -INFINITY;
        int li = 0x7FFFFFFF, lpos = -1;
        #pragma unroll
        for (int j = 0; j < 4; j++) {
            const int p = tid * 4 + j;
            const float v2 = sv[p];
            const int i2 = si[p];
            if (v2 > lv || (v2 == lv && i2 < li)) { lv = v2; li = i2; lpos = p; }
        }
        rv[tid] = lv; ri[tid] = li; rp[tid] = lpos;
        __syncthreads();
        for (int st = 128; st >= 1; st >>= 1) {
            if (tid < st) {
                const float v2 = rv[tid + st];
                const int i2 = ri[tid + st];
                if (v2 > rv[tid] || (v2 == rv[tid] && i2 < ri[tid])) {
                    rv[tid] = v2; ri[tid] = i2; rp[tid] = rp[tid + st];
                }
            }
            __syncthreads();
        }
        if (tid == 0) {
            wv[rr] = rv[0]; wi[rr] = ri[0];
            sv[rp[0]] = -INFINITY; si[rp[0]] = 0x7FFFFFFF;
        }
        __syncthreads();
    }

    if (tid < 4) {
        const int ix = wi[tid];
        const int k = ix / 32000;
        const int v = ix - k * 32000;
        par[tid] = k;
        parents_t[b * 4 + tid] = k;
        toks_t[b * 4 + tid] = v;
        cum[b * 4 + tid] = wv[tid];
        tok[b * 4 + tid] = v;
        fin[b * 4 + tid] = (oldfin[k] || (v == EOS_ID)) ? 1 : 0;
    }
    __syncthreads();

    // gather beam states by parent
    for (int idx = tid; idx < 4 * 512; idx += 256) {
        const int j = idx >> 9, col = idx & 511;
        const int sr = b * 4 + par[j], dr = b * 4 + j;
        h_buf[(size_t)dr * 512 + col] = Acat[(size_t)sr * 1024 + col];
        c_buf[(size_t)dr * 512 + col] = c_new[(size_t)sr * 512 + col];
        attn_buf[(size_t)dr * 512 + col] = attn_new[(size_t)sr * 512 + col];
    }
}

// ---------------------------------------------------------------------------
// gather_tree backtrack: out[b][t][k] int32
// ---------------------------------------------------------------------------
__global__ void __launch_bounds__(128) backtrack_k(
    const int* __restrict__ parents, const int* __restrict__ toks,
    int* __restrict__ out)
{
    const int tid = threadIdx.x;
    if (tid >= 128) return;
    const int b = tid >> 2, kc = tid & 3;
    int ptr = kc;
    for (int t = 47; t >= 0; --t) {
        out[b * 192 + t * 4 + kc] = toks[t * 128 + b * 4 + ptr];
        ptr = parents[t * 128 + b * 4 + ptr];
    }
}

// ---------------------------------------------------------------------------
extern "C" void kernel_launch(void* const* d_in, const int* in_sizes, int n_in,
                              void* d_out, int out_size, void* d_ws, size_t ws_size,
                              hipStream_t stream)
{
    (void)in_sizes; (void)n_in; (void)out_size; (void)ws_size;
    const int* enc_in = (const int*)d_in[0];
    // d_in[1] = decoder_inputs (unused by reference)
    const float* enc_emb = (const float*)d_in[2];
    const float* dec_emb = (const float*)d_in[3];
    const float* W_enc = (const float*)d_in[4];
    const float* U_enc = (const float*)d_in[5];
    const float* b_enc = (const float*)d_in[6];
    const float* W_dec = (const float*)d_in[7];
    const float* U_dec = (const float*)d_in[8];
    const float* b_dec = (const float*)d_in[9];
    const float* W_mem = (const float*)d_in[10];
    const float* W_attn = (const float*)d_in[11];
    const float* W_out = (const float*)d_in[12];
    const float* b_out = (const float*)d_in[13];
    int* out = (int*)d_out;

    char* ws = (char*)d_ws;
    size_t off = 0;
    auto alloc = [&](size_t bytes) -> char* {
        char* p = ws + off;
        off = (off + bytes + 255) & ~(size_t)255;
        return p;
    };
    float* Xz       = (float*)alloc(128ull * 32 * 2048 * 4);  // [t][b][2048]
    float* enc_out  = (float*)alloc(32ull * 128 * 512 * 4);   // [b][s][512]
    float* keys     = (float*)alloc(32ull * 128 * 512 * 4);
    float* enc_c    = (float*)alloc(32ull * 512 * 4);
    float* hzero    = (float*)alloc(512 * 4);
    float* h_buf    = (float*)alloc(128ull * 512 * 4);
    float* c_buf    = (float*)alloc(128ull * 512 * 4);
    float* attn_buf = (float*)alloc(128ull * 512 * 4);
    float* z_dec    = (float*)alloc(128ull * 2048 * 4);
    float* c_new    = (float*)alloc(128ull * 512 * 4);
    float* Acat     = (float*)alloc(128ull * 1024 * 4);
    float* attn_new = (float*)alloc(128ull * 512 * 4);
    float* logits   = (float*)alloc(128ull * 32000 * 4);
    float* cum      = (float*)alloc(128 * 4);
    int* fin        = (int*)alloc(128 * 4);
    int* tok        = (int*)alloc(128 * 4);
    int* parents    = (int*)alloc(48 * 128 * 4);
    int* toks       = (int*)alloc(48 * 128 * 4);

    init_misc_k<<<66, 256, 0, stream>>>(enc_c, hzero);

    // Xz = embed(enc_in) @ W_enc + b_enc   (rows r = s*32+b)
    gemm_k<64, 64, 16, 2><<<dim3(2048 / 64, 4096 / 64), 256, 0, stream>>>(
        enc_emb, W_enc, W_enc, 512, b_enc, Xz, 4096, 2048, 512,
        enc_in, nullptr, nullptr);

    for (int t = 0; t < 128; t++) {
        const float* hprev = t ? (enc_out + (size_t)(t - 1) * 512) : hzero;
        const long hstride = t ? (long)(128 * 512) : 0;
        enc_step_k<<<dim3(8, 16), 256, 0, stream>>>(
            Xz + (size_t)t * 32 * 2048, hprev, hstride, U_enc, enc_c,
            enc_out + (size_t)t * 512, t);
    }

    // keys = enc_out @ W_mem
    gemm_k<64, 64, 16, 0><<<dim3(512 / 64, 4096 / 64), 256, 0, stream>>>(
        enc_out, W_mem, W_mem, 512, nullptr, keys, 4096, 512, 512,
        nullptr, nullptr, nullptr);

    init_dec_k<<<256, 256, 0, stream>>>(enc_out, enc_c, h_buf, c_buf, attn_buf,
                                        cum, fin, tok);

    for (int t = 0; t < 48; t++) {
        // z = [dec_emb[tok], attn, h] @ [W_dec; U_dec] + b_dec
        gemm_k<32, 64, 16, 1><<<dim3(2048 / 64, 128 / 32), 256, 0, stream>>>(
            dec_emb, W_dec, U_dec, 1024, b_dec, z_dec, 128, 2048, 1536,
            tok, attn_buf, h_buf);
        gates_k<<<256, 256, 0, stream>>>(z_dec, c_buf, c_new, Acat);
        attention_k<<<128, 256, 0, stream>>>(Acat, keys, enc_out, Acat);
        // attn_new = [cell_out, ctx] @ W_attn
        gemm_k<32, 64, 16, 0><<<dim3(512 / 64, 128 / 32), 256, 0, stream>>>(
            Acat, W_attn, W_attn, 1024, nullptr, attn_new, 128, 512, 1024,
            nullptr, nullptr, nullptr);
        // logits = attn_new @ W_out + b_out
        gemm_k<64, 64, 16, 0><<<dim3(32000 / 64, 128 / 64), 256, 0, stream>>>(
            attn_new, W_out, W_out, 512, b_out, logits, 128, 32000, 512,
            nullptr, nullptr, nullptr);
        topk_gather_k<<<32, 256, 0, stream>>>(
            logits, cum, fin, tok, Acat, c_new, attn_new,
            h_buf, c_buf, attn_buf, parents + t * 128, toks + t * 128);
    }

    backtrack_k<<<1, 128, 0, stream>>>(parents, toks, out);
}

// Round 2
// 16200.124 us; speedup vs baseline: 1.7895x; 1.7895x over previous
//
#include <hip/hip_runtime.h>
#include <math.h>

#define EOS_ID 2
#define START_ID 1
#define NEGV (-1e9f)

__device__ __forceinline__ float sigmoidf_(float x) { return 1.f / (1.f + expf(-x)); }

// merge two desc-sorted (val, col) top-4 lists; tie: lower col wins. Result into l*.
__device__ __forceinline__ void merge4_(float lv[4], int lc[4],
                                        const float rv[4], const int rc[4]) {
    float ov[4]; int oc[4];
    int ai = 0, bi = 0;
    #pragma unroll
    for (int o = 0; o < 4; o++) {
        const float avv = (ai == 0) ? lv[0] : (ai == 1) ? lv[1] : (ai == 2) ? lv[2] : lv[3];
        const int   acc = (ai == 0) ? lc[0] : (ai == 1) ? lc[1] : (ai == 2) ? lc[2] : lc[3];
        const float bvv = (bi == 0) ? rv[0] : (bi == 1) ? rv[1] : (bi == 2) ? rv[2] : rv[3];
        const int   bcc = (bi == 0) ? rc[0] : (bi == 1) ? rc[1] : (bi == 2) ? rc[2] : rc[3];
        const bool ta = (avv > bvv) || (avv == bvv && acc < bcc);
        ov[o] = ta ? avv : bvv;
        oc[o] = ta ? acc : bcc;
        if (ta) ai++; else bi++;
    }
    #pragma unroll
    for (int o = 0; o < 4; o++) { lv[o] = ov[o]; lc[o] = oc[o]; }
}

__device__ __forceinline__ void lse_combine_(float& m, float& s, float m2, float s2) {
    const float M = fmaxf(m, m2);
    s = s * expf(m - M) + s2 * expf(m2 - M);
    m = M;
}

// ---------------------------------------------------------------------------
// Generic fp32 GEMM: C[M,N] = A[M,K] @ B[K,N] (+bias)
// AMODE 0: plain A. AMODE 2: encoder embedding gather (row r=s*32+b, tok[b*128+s])
// TRANS 1: store C transposed as keysT[b][n][s] with r = b*128+s  (no bias)
// ---------------------------------------------------------------------------
template<int BM, int BN, int BK, int AMODE, int TRANS>
__global__ void __launch_bounds__(256) gemm_k(
    const float* __restrict__ A, const float* __restrict__ B,
    const float* __restrict__ bias, float* __restrict__ C,
    int M, int N, int K, const int* __restrict__ tokp)
{
    static_assert(BN == 64, "");
    constexpr int TM = BM / 16, TN = BN / 16;
    __shared__ __align__(16) float As[BK][BM];
    __shared__ __align__(16) float Bs[BK][BN];
    const int tid = threadIdx.x;
    const int n0 = blockIdx.x * BN, m0 = blockIdx.y * BM;
    const int tx = tid & 15, ty = tid >> 4;
    (void)M;

    float acc[TM][TN];
    #pragma unroll
    for (int i = 0; i < TM; i++)
        #pragma unroll
        for (int j = 0; j < TN; j++) acc[i][j] = 0.f;

    constexpr int A4 = BM * BK / 4;

    for (int k0 = 0; k0 < K; k0 += BK) {
        if (A4 >= 256 || tid < A4) {
            const int am  = tid / (BK / 4);
            const int ak4 = tid % (BK / 4);
            const int kg  = k0 + ak4 * 4;
            float4 av;
            if (AMODE == 0) {
                av = *reinterpret_cast<const float4*>(A + (size_t)(m0 + am) * K + kg);
            } else {  // AMODE 2
                const int r = m0 + am;
                const int s = r >> 5, b = r & 31;
                av = *reinterpret_cast<const float4*>(
                    A + (size_t)tokp[b * 128 + s] * 512 + kg);
            }
            As[ak4 * 4 + 0][am] = av.x;
            As[ak4 * 4 + 1][am] = av.y;
            As[ak4 * 4 + 2][am] = av.z;
            As[ak4 * 4 + 3][am] = av.w;
        }
        {
            const int bk = tid >> 4, bn4 = tid & 15;
            *reinterpret_cast<float4*>(&Bs[bk][bn4 * 4]) =
                *reinterpret_cast<const float4*>(B + (size_t)(k0 + bk) * N + n0 + bn4 * 4);
        }
        __syncthreads();
        #pragma unroll
        for (int kk = 0; kk < BK; kk++) {
            float af[TM], bf[TN];
            if constexpr (TM == 4) {
                const float4 t4 = *reinterpret_cast<const float4*>(&As[kk][ty * TM]);
                af[0] = t4.x; af[1] = t4.y; af[2] = t4.z; af[3] = t4.w;
            } else if constexpr (TM == 2) {
                const float2 t2 = *reinterpret_cast<const float2*>(&As[kk][ty * TM]);
                af[0] = t2.x; af[1] = t2.y;
            } else {
                af[0] = As[kk][ty];
            }
            const float4 b4 = *reinterpret_cast<const float4*>(&Bs[kk][tx * TN]);
            bf[0] = b4.x; bf[1] = b4.y; bf[2] = b4.z; bf[3] = b4.w;
            #pragma unroll
            for (int i = 0; i < TM; i++)
                #pragma unroll
                for (int j = 0; j < TN; j++) acc[i][j] += af[i] * bf[j];
        }
        __syncthreads();
    }

    if constexpr (TRANS) {
        #pragma unroll
        for (int i = 0; i < TM; i++) {
            const int r = m0 + ty * TM + i;
            const int b = r >> 7, s = r & 127;
            #pragma unroll
            for (int j = 0; j < TN; j++)
                C[((size_t)b * 512 + (n0 + tx * TN + j)) * 128 + s] = acc[i][j];
        }
    } else {
        float bv[TN];
        #pragma unroll
        for (int j = 0; j < TN; j++) bv[j] = bias ? bias[n0 + tx * TN + j] : 0.f;
        #pragma unroll
        for (int i = 0; i < TM; i++) {
            float4 o;
            o.x = acc[i][0] + bv[0]; o.y = acc[i][1] + bv[1];
            o.z = acc[i][2] + bv[2]; o.w = acc[i][3] + bv[3];
            *reinterpret_cast<float4*>(C + (size_t)(m0 + ty * TM + i) * N + n0 + tx * TN) = o;
        }
    }
}

// ---------------------------------------------------------------------------
// One-time pack: Bp[k][j*4+g] = (k<1024 ? W_dec : U_dec)[.][g*512+j]; bp likewise
// ---------------------------------------------------------------------------
__global__ void __launch_bounds__(256) pack_dec_k(
    const float* __restrict__ W_dec, const float* __restrict__ U_dec,
    const float* __restrict__ b_dec, float* __restrict__ Bp, float* __restrict__ bp)
{
    const int idx = blockIdx.x * 256 + threadIdx.x;
    if (idx < 1536 * 2048) {
        const int k = idx >> 11, cp = idx & 2047;
        const int j = cp >> 2, g = cp & 3;
        const int sc = g * 512 + j;
        Bp[idx] = (k < 1024) ? W_dec[(size_t)k * 2048 + sc]
                             : U_dec[(size_t)(k - 1024) * 2048 + sc];
        if (idx < 2048) bp[idx] = b_dec[sc];
    }
}

// ---------------------------------------------------------------------------
// init: zero enc_c [32*512] and hzero [512]
// ---------------------------------------------------------------------------
__global__ void __launch_bounds__(256) init_misc_k(float* __restrict__ enc_c,
                                                   float* __restrict__ hzero)
{
    const int idx = blockIdx.x * 256 + threadIdx.x;
    if (idx < 32 * 512) enc_c[idx] = 0.f;
    if (idx < 512) hzero[idx] = 0.f;
}

// ---------------------------------------------------------------------------
// Encoder LSTM step. Grid (8 jtiles, 16 bgroups), block 256.
// ---------------------------------------------------------------------------
__global__ void __launch_bounds__(256) enc_step_k(
    const float* __restrict__ Xz_t, const float* __restrict__ hprev, long hstride,
    const float* __restrict__ U, float* __restrict__ c, float* __restrict__ hout)
{
    __shared__ __align__(16) float hs[512][2];
    __shared__ float zst[2][4][64];
    const int tid = threadIdx.x;
    const int jt = blockIdx.x;
    const int b0 = blockIdx.y * 2;

    {
        const int bb = tid >> 7, k4 = tid & 127;
        const float4 hv = *reinterpret_cast<const float4*>(
            hprev + (size_t)(b0 + bb) * hstride + k4 * 4);
        hs[k4 * 4 + 0][bb] = hv.x; hs[k4 * 4 + 1][bb] = hv.y;
        hs[k4 * 4 + 2][bb] = hv.z; hs[k4 * 4 + 3][bb] = hv.w;
    }
    __syncthreads();

    const int j = tid & 63, g = tid >> 6;
    const int col = g * 512 + jt * 64 + j;
    float a0 = Xz_t[(size_t)b0 * 2048 + col];
    float a1 = Xz_t[(size_t)(b0 + 1) * 2048 + col];
    #pragma unroll 8
    for (int k = 0; k < 512; k++) {
        const float u = U[(size_t)k * 2048 + col];
        const float2 h2 = *reinterpret_cast<const float2*>(&hs[k][0]);
        a0 += h2.x * u;
        a1 += h2.y * u;
    }
    zst[0][g][j] = a0;
    zst[1][g][j] = a1;
    __syncthreads();

    if (tid < 128) {
        const int bb = tid >> 6, jj = tid & 63;
        const int b = b0 + bb;
        const float iv = sigmoidf_(zst[bb][0][jj]);
        const float fv = sigmoidf_(zst[bb][1][jj]);
        const float gv = tanhf(zst[bb][2][jj]);
        const float ov = sigmoidf_(zst[bb][3][jj]);
        const int jglob = jt * 64 + jj;
        const size_t ci = (size_t)b * 512 + jglob;
        const float cv = fv * c[ci] + iv * gv;
        c[ci] = cv;
        hout[(size_t)b * 128 * 512 + jglob] = ov * tanhf(cv);
    }
}

// ---------------------------------------------------------------------------
// Decoder init
// ---------------------------------------------------------------------------
__global__ void __launch_bounds__(256) init_dec_k(
    const float* __restrict__ enc_out, const float* __restrict__ enc_c,
    float* __restrict__ h_buf, float* __restrict__ c_buf, float* __restrict__ attn_buf,
    float* __restrict__ cum, int* __restrict__ fin, int* __restrict__ tok)
{
    const int idx = blockIdx.x * 256 + threadIdx.x;
    const int r = idx >> 9, jcol = idx & 511;
    const int b = r >> 2, kbeam = r & 3;
    h_buf[idx] = enc_out[((size_t)b * 128 + 127) * 512 + jcol];
    c_buf[idx] = enc_c[(size_t)b * 512 + jcol];
    attn_buf[idx] = 0.f;
    if (jcol == 0) {
        cum[r] = (kbeam == 0) ? 0.f : NEGV;
        fin[r] = 0;
        tok[r] = START_ID;
    }
}

// ---------------------------------------------------------------------------
// z GEMM with concat-gather A and fused LSTM gate epilogue (packed B).
// BM=16, BN=64, BK=16. Grid (32, 8). A = [emb(tok) | attn | h], K=1536.
// ---------------------------------------------------------------------------
__global__ void __launch_bounds__(256) zgemm_gates_k(
    const float* __restrict__ dec_emb, const float* __restrict__ Bp,
    const float* __restrict__ bp, const int* __restrict__ tok,
    const float* __restrict__ attn_buf, const float* __restrict__ h_buf,
    const float* __restrict__ c_buf, float* __restrict__ c_new,
    float* __restrict__ Acat)
{
    constexpr int BM = 16, BN = 64, BK = 16;
    __shared__ __align__(16) float As[BK][BM];
    __shared__ __align__(16) float Bs[BK][BN];
    const int tid = threadIdx.x;
    const int n0 = blockIdx.x * BN, m0 = blockIdx.y * BM;
    const int tx = tid & 15, ty = tid >> 4;

    float acc[4] = {0.f, 0.f, 0.f, 0.f};

    for (int k0 = 0; k0 < 1536; k0 += BK) {
        if (tid < 64) {
            const int am = tid >> 2, ak4 = tid & 3;
            const int kg = k0 + ak4 * 4;
            const int r = m0 + am;
            float4 av;
            if (kg < 512)
                av = *reinterpret_cast<const float4*>(dec_emb + (size_t)tok[r] * 512 + kg);
            else if (kg < 1024)
                av = *reinterpret_cast<const float4*>(attn_buf + (size_t)r * 512 + (kg - 512));
            else
                av = *reinterpret_cast<const float4*>(h_buf + (size_t)r * 512 + (kg - 1024));
            As[ak4 * 4 + 0][am] = av.x;
            As[ak4 * 4 + 1][am] = av.y;
            As[ak4 * 4 + 2][am] = av.z;
            As[ak4 * 4 + 3][am] = av.w;
        }
        {
            const int bk = tid >> 4, bn4 = tid & 15;
            *reinterpret_cast<float4*>(&Bs[bk][bn4 * 4]) =
                *reinterpret_cast<const float4*>(Bp + (size_t)(k0 + bk) * 2048 + n0 + bn4 * 4);
        }
        __syncthreads();
        #pragma unroll
        for (int kk = 0; kk < BK; kk++) {
            const float a = As[kk][ty];
            const float4 b4 = *reinterpret_cast<const float4*>(&Bs[kk][tx * 4]);
            acc[0] += a * b4.x; acc[1] += a * b4.y;
            acc[2] += a * b4.z; acc[3] += a * b4.w;
        }
        __syncthreads();
    }

    const int r = m0 + ty;
    const int j = (n0 >> 2) + tx;
    const float iv = sigmoidf_(acc[0] + bp[n0 + tx * 4 + 0]);
    const float fv = sigmoidf_(acc[1] + bp[n0 + tx * 4 + 1]);
    const float gv = tanhf   (acc[2] + bp[n0 + tx * 4 + 2]);
    const float ov = sigmoidf_(acc[3] + bp[n0 + tx * 4 + 3]);
    const float cv = fv * c_buf[(size_t)r * 512 + j] + iv * gv;
    c_new[(size_t)r * 512 + j] = cv;
    Acat[(size_t)r * 1024 + j] = ov * tanhf(cv);
}

// ---------------------------------------------------------------------------
// Attention with transposed keys (coalesced). Grid 128, block 256.
// ---------------------------------------------------------------------------
__global__ void __launch_bounds__(256) attention_k(
    const float* __restrict__ Acat, const float* __restrict__ keysT,
    const float* __restrict__ enc_out, float* __restrict__ AcatW)
{
    __shared__ __align__(16) float q[512];
    __shared__ float scp[2][128];
    __shared__ float sc[128];
    __shared__ float red[128];
    const int r = blockIdx.x;
    const int b = r >> 2;
    const int tid = threadIdx.x;

    if (tid < 128)
        reinterpret_cast<float4*>(q)[tid] =
            reinterpret_cast<const float4*>(Acat + (size_t)r * 1024)[tid];
    __syncthreads();

    {
        const int half = tid >> 7, s = tid & 127;
        const float* kp = keysT + ((size_t)b * 512 + half * 256) * 128 + s;
        float acc = 0.f;
        #pragma unroll 8
        for (int kk = 0; kk < 256; kk++) acc += q[half * 256 + kk] * kp[(size_t)kk * 128];
        scp[half][s] = acc;
    }
    __syncthreads();
    if (tid < 128) sc[tid] = scp[0][tid] + scp[1][tid];
    __syncthreads();
    if (tid < 64) red[tid] = fmaxf(sc[tid], sc[tid + 64]);
    __syncthreads();
    for (int st = 32; st >= 1; st >>= 1) {
        if (tid < st) red[tid] = fmaxf(red[tid], red[tid + st]);
        __syncthreads();
    }
    const float m = red[0];
    __syncthreads();
    if (tid < 128) sc[tid] = expf(sc[tid] - m);
    __syncthreads();
    if (tid < 64) red[tid] = sc[tid] + sc[tid + 64];
    __syncthreads();
    for (int st = 32; st >= 1; st >>= 1) {
        if (tid < st) red[tid] += red[tid + st];
        __syncthreads();
    }
    const float S = red[0];
    __syncthreads();
    if (tid < 128) sc[tid] = sc[tid] / S;
    __syncthreads();

    float a0 = 0.f, a1 = 0.f;
    for (int s = 0; s < 128; s++) {
        const float w = sc[s];
        const float* vr = enc_out + ((size_t)b * 128 + s) * 512;
        a0 += w * vr[tid];
        a1 += w * vr[tid + 256];
    }
    AcatW[(size_t)r * 1024 + 512 + tid] = a0;
    AcatW[(size_t)r * 1024 + 512 + tid + 256] = a1;
}

// ---------------------------------------------------------------------------
// Logits GEMM (BM=128 x BN=64, K=512) with fused per-row-per-tile partials:
// rowmax, sumexp(rel max), top-4 (val desc, col asc). Logits never hit memory.
// Grid 500 (1D). pmax/psum: [128][512]; pval/pcol: [128*4][512].
// ---------------------------------------------------------------------------
__global__ void __launch_bounds__(256) logits_top_k(
    const float* __restrict__ A, const float* __restrict__ B,
    const float* __restrict__ bias, float* __restrict__ pmax,
    float* __restrict__ psum, float* __restrict__ pval, int* __restrict__ pcol)
{
    constexpr int BK = 16;
    __shared__ __align__(16) float As[BK][128];
    __shared__ __align__(16) float Bs[BK][64];
    const int tid = threadIdx.x;
    const int n0 = blockIdx.x * 64;
    const int t = blockIdx.x;
    const int tx = tid & 15, ty = tid >> 4;

    float acc[8][4];
    #pragma unroll
    for (int i = 0; i < 8; i++)
        #pragma unroll
        for (int j = 0; j < 4; j++) acc[i][j] = 0.f;

    for (int k0 = 0; k0 < 512; k0 += BK) {
        #pragma unroll
        for (int p = 0; p < 2; p++) {
            const int idx = p * 256 + tid;
            const int am = idx >> 2, ak4 = idx & 3;
            const float4 av = *reinterpret_cast<const float4*>(
                A + (size_t)am * 512 + k0 + ak4 * 4);
            As[ak4 * 4 + 0][am] = av.x;
            As[ak4 * 4 + 1][am] = av.y;
            As[ak4 * 4 + 2][am] = av.z;
            As[ak4 * 4 + 3][am] = av.w;
        }
        {
            const int bk = tid >> 4, bn4 = tid & 15;
            *reinterpret_cast<float4*>(&Bs[bk][bn4 * 4]) =
                *reinterpret_cast<const float4*>(B + (size_t)(k0 + bk) * 32000 + n0 + bn4 * 4);
        }
        __syncthreads();
        #pragma unroll
        for (int kk = 0; kk < BK; kk++) {
            float af[8];
            const float4 t0 = *reinterpret_cast<const float4*>(&As[kk][ty * 8]);
            const float4 t1 = *reinterpret_cast<const float4*>(&As[kk][ty * 8 + 4]);
            af[0] = t0.x; af[1] = t0.y; af[2] = t0.z; af[3] = t0.w;
            af[4] = t1.x; af[5] = t1.y; af[6] = t1.z; af[7] = t1.w;
            const float4 b4 = *reinterpret_cast<const float4*>(&Bs[kk][tx * 4]);
            #pragma unroll
            for (int i = 0; i < 8; i++) {
                acc[i][0] += af[i] * b4.x; acc[i][1] += af[i] * b4.y;
                acc[i][2] += af[i] * b4.z; acc[i][3] += af[i] * b4.w;
            }
        }
        __syncthreads();
    }

    float bv[4];
    #pragma unroll
    for (int j = 0; j < 4; j++) bv[j] = bias[n0 + tx * 4 + j];

    #pragma unroll
    for (int i = 0; i < 8; i++) {
        const int r = ty * 8 + i;
        float lv[4]; int lc[4];
        #pragma unroll
        for (int j = 0; j < 4; j++) { lv[j] = acc[i][j] + bv[j]; lc[j] = n0 + tx * 4 + j; }
        // row max across 4 local + 16 lanes of this row group
        float rm = fmaxf(fmaxf(lv[0], lv[1]), fmaxf(lv[2], lv[3]));
        #pragma unroll
        for (int d = 1; d <= 8; d <<= 1) rm = fmaxf(rm, __shfl_xor(rm, d));
        float s4 = expf(lv[0] - rm) + expf(lv[1] - rm) + expf(lv[2] - rm) + expf(lv[3] - rm);
        #pragma unroll
        for (int d = 1; d <= 8; d <<= 1) s4 += __shfl_xor(s4, d);
        // local stable sort desc (cols ascending -> tie keeps lower col)
        #pragma unroll
        for (int p = 0; p < 3; p++)
            #pragma unroll
            for (int q = 0; q < 3 - p; q++)
                if (lv[q + 1] > lv[q]) {
                    const float tv = lv[q]; lv[q] = lv[q + 1]; lv[q + 1] = tv;
                    const int tc = lc[q]; lc[q] = lc[q + 1]; lc[q + 1] = tc;
                }
        #pragma unroll
        for (int d = 1; d <= 8; d <<= 1) {
            float rv[4]; int rc[4];
            #pragma unroll
            for (int j = 0; j < 4; j++) {
                rv[j] = __shfl_xor(lv[j], d);
                rc[j] = __shfl_xor(lc[j], d);
            }
            merge4_(lv, lc, rv, rc);
        }
        if (tx == 0) {
            pmax[r * 512 + t] = rm;
            psum[r * 512 + t] = s4;
            #pragma unroll
            for (int j = 0; j < 4; j++) {
                pval[(r * 4 + j) * 512 + t] = lv[j];
                pcol[(r * 4 + j) * 512 + t] = lc[j];
            }
        }
    }
}

// ---------------------------------------------------------------------------
// Per-batch: merge 500 tile-partials for the 4 beam rows (lockstep, 4x256
// threads), then beam top-4 with exact jax tie-break, then state gather.
// Grid 32, block 1024.
// ---------------------------------------------------------------------------
__global__ void __launch_bounds__(1024) merge_update_k(
    const float* __restrict__ pmax, const float* __restrict__ psum,
    const float* __restrict__ pval, const int* __restrict__ pcol,
    float* __restrict__ cum, int* __restrict__ fin, int* __restrict__ tok,
    const float* __restrict__ Acat, const float* __restrict__ c_new,
    const float* __restrict__ attn_new,
    float* __restrict__ h_buf, float* __restrict__ c_buf, float* __restrict__ attn_buf,
    int* __restrict__ parents_t, int* __restrict__ toks_t)
{
    const int b = blockIdx.x;
    const int tid = threadIdx.x;
    const int rloc = tid >> 8, lt = tid & 255;
    const int r = b * 4 + rloc;

    __shared__ float sm[4][256], ss[4][256];
    __shared__ float sv[4][256][4];
    __shared__ int   sc4[4][256][4];
    __shared__ float rowlse[4], rowv[4][4];
    __shared__ int   rowc[4][4];
    __shared__ float oldcum[4];
    __shared__ int   oldfin[4], par[4];

    if (tid < 4) {
        oldcum[tid] = cum[b * 4 + tid];
        oldfin[tid] = fin[b * 4 + tid];
    }

    float m = -INFINITY, s = 0.f;
    float lv[4] = {-INFINITY, -INFINITY, -INFINITY, -INFINITY};
    int lc[4] = {0x7FFFFFFF, 0x7FFFFFFF, 0x7FFFFFFF, 0x7FFFFFFF};
    for (int t = lt; t < 500; t += 256) {
        lse_combine_(m, s, pmax[r * 512 + t], psum[r * 512 + t]);
        float rv[4]; int rc[4];
        #pragma unroll
        for (int j = 0; j < 4; j++) {
            rv[j] = pval[(r * 4 + j) * 512 + t];
            rc[j] = pcol[(r * 4 + j) * 512 + t];
        }
        merge4_(lv, lc, rv, rc);
    }
    sm[rloc][lt] = m; ss[rloc][lt] = s;
    #pragma unroll
    for (int j = 0; j < 4; j++) { sv[rloc][lt][j] = lv[j]; sc4[rloc][lt][j] = lc[j]; }
    __syncthreads();

    for (int st = 128; st >= 1; st >>= 1) {
        if (lt < st) {
            float m2 = sm[rloc][lt + st], s2 = ss[rloc][lt + st];
            lse_combine_(m, s, m2, s2);
            sm[rloc][lt] = m; ss[rloc][lt] = s;
            float rv[4]; int rc[4];
            #pragma unroll
            for (int j = 0; j < 4; j++) {
                rv[j] = sv[rloc][lt + st][j];
                rc[j] = sc4[rloc][lt + st][j];
            }
            merge4_(lv, lc, rv, rc);
            #pragma unroll
            for (int j = 0; j < 4; j++) { sv[rloc][lt][j] = lv[j]; sc4[rloc][lt][j] = lc[j]; }
        }
        __syncthreads();
    }
    if (lt == 0) {
        rowlse[rloc] = m + logf(s);
        #pragma unroll
        for (int j = 0; j < 4; j++) { rowv[rloc][j] = lv[j]; rowc[rloc][j] = lc[j]; }
    }
    __syncthreads();

    if (tid == 0) {
        float cv[16]; int ci[16];
        const int fillv[3] = {0, 1, 3};
        for (int k = 0; k < 4; k++) {
            if (oldfin[k]) {
                cv[k * 4 + 0] = oldcum[k];
                ci[k * 4 + 0] = k * 32000 + EOS_ID;
                for (int j = 1; j < 4; j++) {
                    cv[k * 4 + j] = oldcum[k] + NEGV;
                    ci[k * 4 + j] = k * 32000 + fillv[j - 1];
                }
            } else {
                const float lse = rowlse[k];
                for (int j = 0; j < 4; j++) {
                    cv[k * 4 + j] = oldcum[k] + (rowv[k][j] - lse);
                    ci[k * 4 + j] = k * 32000 + rowc[k][j];
                }
            }
        }
        for (int rr = 0; rr < 4; rr++) {
            float bvv = -INFINITY; int bix = 0x7FFFFFFF, bp_ = -1;
            for (int q = 0; q < 16; q++) {
                if (cv[q] > bvv || (cv[q] == bvv && ci[q] < bix)) {
                    bvv = cv[q]; bix = ci[q]; bp_ = q;
                }
            }
            cv[bp_] = -INFINITY; ci[bp_] = 0x7FFFFFFF;
            const int k = bix / 32000, v = bix - k * 32000;
            par[rr] = k;
            parents_t[b * 4 + rr] = k;
            toks_t[b * 4 + rr] = v;
            cum[b * 4 + rr] = bvv;
            tok[b * 4 + rr] = v;
            fin[b * 4 + rr] = (oldfin[k] || v == EOS_ID) ? 1 : 0;
        }
    }
    __syncthreads();

    for (int idx = tid; idx < 4 * 512; idx += 1024) {
        const int j = idx >> 9, col = idx & 511;
        const int sr = b * 4 + par[j], dr = b * 4 + j;
        h_buf[(size_t)dr * 512 + col] = Acat[(size_t)sr * 1024 + col];
        c_buf[(size_t)dr * 512 + col] = c_new[(size_t)sr * 512 + col];
        attn_buf[(size_t)dr * 512 + col] = attn_new[(size_t)sr * 512 + col];
    }
}

// ---------------------------------------------------------------------------
__global__ void __launch_bounds__(128) backtrack_k(
    const int* __restrict__ parents, const int* __restrict__ toks,
    int* __restrict__ out)
{
    const int tid = threadIdx.x;
    const int b = tid >> 2, kc = tid & 3;
    int ptr = kc;
    for (int t = 47; t >= 0; --t) {
        out[b * 192 + t * 4 + kc] = toks[t * 128 + b * 4 + ptr];
        ptr = parents[t * 128 + b * 4 + ptr];
    }
}

// ---------------------------------------------------------------------------
extern "C" void kernel_launch(void* const* d_in, const int* in_sizes, int n_in,
                              void* d_out, int out_size, void* d_ws, size_t ws_size,
                              hipStream_t stream)
{
    (void)in_sizes; (void)n_in; (void)out_size; (void)ws_size;
    const int* enc_in = (const int*)d_in[0];
    const float* enc_emb = (const float*)d_in[2];
    const float* dec_emb = (const float*)d_in[3];
    const float* W_enc = (const float*)d_in[4];
    const float* U_enc = (const float*)d_in[5];
    const float* b_enc = (const float*)d_in[6];
    const float* W_dec = (const float*)d_in[7];
    const float* U_dec = (const float*)d_in[8];
    const float* b_dec = (const float*)d_in[9];
    const float* W_mem = (const float*)d_in[10];
    const float* W_attn = (const float*)d_in[11];
    const float* W_out = (const float*)d_in[12];
    const float* b_out = (const float*)d_in[13];
    int* out = (int*)d_out;

    char* ws = (char*)d_ws;
    size_t off = 0;
    auto alloc = [&](size_t bytes) -> char* {
        char* p = ws + off;
        off = (off + bytes + 255) & ~(size_t)255;
        return p;
    };
    float* Xz       = (float*)alloc(128ull * 32 * 2048 * 4);
    float* enc_out  = (float*)alloc(32ull * 128 * 512 * 4);
    float* keysT    = (float*)alloc(32ull * 512 * 128 * 4);
    float* Bp       = (float*)alloc(1536ull * 2048 * 4);
    float* bp       = (float*)alloc(2048 * 4);
    float* enc_c    = (float*)alloc(32ull * 512 * 4);
    float* hzero    = (float*)alloc(512 * 4);
    float* h_buf    = (float*)alloc(128ull * 512 * 4);
    float* c_buf    = (float*)alloc(128ull * 512 * 4);
    float* attn_buf = (float*)alloc(128ull * 512 * 4);
    float* c_new    = (float*)alloc(128ull * 512 * 4);
    float* Acat     = (float*)alloc(128ull * 1024 * 4);
    float* attn_new = (float*)alloc(128ull * 512 * 4);
    float* pmax     = (float*)alloc(128ull * 512 * 4);
    float* psum     = (float*)alloc(128ull * 512 * 4);
    float* pval     = (float*)alloc(512ull * 512 * 4);
    int*   pcol     = (int*)alloc(512ull * 512 * 4);
    float* cum      = (float*)alloc(128 * 4);
    int* fin        = (int*)alloc(128 * 4);
    int* tok        = (int*)alloc(128 * 4);
    int* parents    = (int*)alloc(48 * 128 * 4);
    int* toks       = (int*)alloc(48 * 128 * 4);

    init_misc_k<<<66, 256, 0, stream>>>(enc_c, hzero);
    pack_dec_k<<<(1536 * 2048) / 256, 256, 0, stream>>>(W_dec, U_dec, b_dec, Bp, bp);

    gemm_k<64, 64, 16, 2, 0><<<dim3(32, 64), 256, 0, stream>>>(
        enc_emb, W_enc, b_enc, Xz, 4096, 2048, 512, enc_in);

    for (int t = 0; t < 128; t++) {
        const float* hprev = t ? (enc_out + (size_t)(t - 1) * 512) : hzero;
        const long hstride = t ? (long)(128 * 512) : 0;
        enc_step_k<<<dim3(8, 16), 256, 0, stream>>>(
            Xz + (size_t)t * 32 * 2048, hprev, hstride, U_enc, enc_c,
            enc_out + (size_t)t * 512);
    }

    gemm_k<64, 64, 16, 0, 1><<<dim3(8, 64), 256, 0, stream>>>(
        enc_out, W_mem, nullptr, keysT, 4096, 512, 512, nullptr);

    init_dec_k<<<256, 256, 0, stream>>>(enc_out, enc_c, h_buf, c_buf, attn_buf,
                                        cum, fin, tok);

    for (int t = 0; t < 48; t++) {
        zgemm_gates_k<<<dim3(32, 8), 256, 0, stream>>>(
            dec_emb, Bp, bp, tok, attn_buf, h_buf, c_buf, c_new, Acat);
        attention_k<<<128, 256, 0, stream>>>(Acat, keysT, enc_out, Acat);
        gemm_k<16, 64, 16, 0, 0><<<dim3(8, 8), 256, 0, stream>>>(
            Acat, W_attn, nullptr, attn_new, 128, 512, 1024, nullptr);
        logits_top_k<<<500, 256, 0, stream>>>(
            attn_new, W_out, b_out, pmax, psum, pval, pcol);
        merge_update_k<<<32, 1024, 0, stream>>>(
            pmax, psum, pval, pcol, cum, fin, tok, Acat, c_new, attn_new,
            h_buf, c_buf, attn_buf, parents + t * 128, toks + t * 128);
    }

    backtrack_k<<<1, 128, 0, stream>>>(parents, toks, out);
}